// Round 5
// baseline (510.378 us; speedup 1.0000x reference)
//
#include <hip/hip_runtime.h>

// Problem constants
#define B_  2
#define S_  4096
#define D_  1024
#define H_  8
#define DK_ 128
#define DV_ 128
#define SEG_ 512
#define NSEG_ 8
#define BH_ 16
#define M_ 8192          // B*S

typedef __attribute__((ext_vector_type(8))) short bf16x8;
typedef __attribute__((ext_vector_type(4))) float f32x4;

__device__ __forceinline__ float elu1(float x) { return x > 0.f ? x + 1.f : __expf(x); }
__device__ __forceinline__ float sigmoidf(float x) { return 1.f / (1.f + __expf(-x)); }

__device__ __forceinline__ unsigned short f2b(float f) {  // RNE fp32->bf16
    union { float f; unsigned int u; } x; x.f = f;
    unsigned int r = x.u + 0x7fffu + ((x.u >> 16) & 1u);
    return (unsigned short)(r >> 16);
}
__device__ __forceinline__ float b2f(unsigned short u) {
    union { unsigned int u; float f; } x; x.u = ((unsigned int)u) << 16; return x.f;
}

__device__ __forceinline__ void gl2lds16(const void* g, void* l) {
    __builtin_amdgcn_global_load_lds(
        (const __attribute__((address_space(1))) void*)g,
        (__attribute__((address_space(3))) void*)l, 16, 0, 0);
}

// ---------------------------------------------------------------------------
// fp32 -> bf16 row-major convert
// ---------------------------------------------------------------------------
__global__ __launch_bounds__(256) void conv_bf16(
    const float* __restrict__ src, unsigned short* __restrict__ dst)
{
    int i = (blockIdx.x * 256 + threadIdx.x) * 4;
    float4 v = *(const float4*)(src + i);
    ushort4 o;
    o.x = f2b(v.x); o.y = f2b(v.y); o.z = f2b(v.z); o.w = f2b(v.w);
    *(ushort4*)(dst + i) = o;
}

// ---------------------------------------------------------------------------
// fp32 (R x C) -> bf16 transposed (C x R). blockIdx.z = matrix index.
// ---------------------------------------------------------------------------
__global__ __launch_bounds__(256) void transpose_conv(
    const float* __restrict__ src, unsigned short* __restrict__ dst, int R, int C)
{
    __shared__ float tile[32][33];
    const size_t moff = (size_t)blockIdx.z * R * C;
    src += moff; dst += moff;
    const int c0 = blockIdx.x * 32, r0 = blockIdx.y * 32;
    const int tx = threadIdx.x & 31, ty = threadIdx.x >> 5;   // 32 x 8
    #pragma unroll
    for (int i = 0; i < 32; i += 8)
        tile[ty + i][tx] = src[(size_t)(r0 + ty + i) * C + c0 + tx];
    __syncthreads();
    #pragma unroll
    for (int i = 0; i < 32; i += 8)
        dst[(size_t)(c0 + ty + i) * R + r0 + tx] = f2b(tile[tx][ty + i]);
}

// ---------------------------------------------------------------------------
// sigma_k^T prep: SkT[bh][dk][s] = f2b(elu1(Kbb[bh][s][dk]))
// ---------------------------------------------------------------------------
__global__ __launch_bounds__(256) void sigma_kT(
    const unsigned short* __restrict__ Kbb, unsigned short* __restrict__ SkT)
{
    __shared__ float tile[32][33];
    const int bh = blockIdx.z;
    const int s0 = blockIdx.x * 32, dk0 = blockIdx.y * 32;
    const int tx = threadIdx.x & 31, ty = threadIdx.x >> 5;   // 32 x 8
    #pragma unroll
    for (int i = 0; i < 32; i += 8)
        tile[ty + i][tx] = elu1(b2f(Kbb[((size_t)bh * 4096 + s0 + ty + i) * 128 + dk0 + tx]));
    __syncthreads();
    #pragma unroll
    for (int i = 0; i < 32; i += 8)
        SkT[((size_t)bh * 128 + dk0 + ty + i) * 4096 + s0 + tx] = f2b(tile[tx][ty + i]);
}

// ---------------------------------------------------------------------------
// bf16 MFMA GEMM core: 128x128 tile, BK=32, 16x16x32 MFMA, 4x4 acc per wave.
// ---------------------------------------------------------------------------
__device__ __forceinline__ void mfma_gemm_128(
    const unsigned short* __restrict__ A, int lda,
    const unsigned short* __restrict__ Bt, int ldb, int K,
    unsigned short* As, unsigned short* Bs, f32x4 acc[4][4])
{
    const int tid = threadIdx.x;
    const int wave = tid >> 6, lane = tid & 63;
    const int r4 = lane >> 2, c4 = (lane & 3) * 8;
    const int lrow = lane & 15, lquad = lane >> 4;
    const int wm = (wave >> 1) * 64, wn = (wave & 1) * 64;
    for (int k0 = 0; k0 < K; k0 += 32) {
        #pragma unroll
        for (int i = 0; i < 2; ++i) {
            int ar = wave * 32 + i * 16;
            gl2lds16(A  + (size_t)(ar + r4) * lda + k0 + c4, As + ar * 32);
            gl2lds16(Bt + (size_t)(ar + r4) * ldb + k0 + c4, Bs + ar * 32);
        }
        __syncthreads();
        bf16x8 af[4], bfr[4];
        #pragma unroll
        for (int i = 0; i < 4; ++i)
            af[i] = *(const bf16x8*)(As + (wm + i * 16 + lrow) * 32 + lquad * 8);
        #pragma unroll
        for (int j = 0; j < 4; ++j)
            bfr[j] = *(const bf16x8*)(Bs + (wn + j * 16 + lrow) * 32 + lquad * 8);
        #pragma unroll
        for (int i = 0; i < 4; ++i)
            #pragma unroll
            for (int j = 0; j < 4; ++j)
                acc[i][j] = __builtin_amdgcn_mfma_f32_16x16x32_bf16(af[i], bfr[j], acc[i][j], 0, 0, 0);
        __syncthreads();
    }
}

// ---------------------------------------------------------------------------
// QKV projection: xb (8192x1024 bf16) @ Wtb[panel] (128x1024 bf16 = W^T)
// Outputs bf16: Qbb/Kbb (BH,S,128) row-major; V only as Vtb (BH,8,128dv,512s).
// ---------------------------------------------------------------------------
__global__ __launch_bounds__(256) void gemm_qkv_mfma(
    const unsigned short* __restrict__ xb, const unsigned short* __restrict__ Wtb,
    unsigned short* __restrict__ Qbb, unsigned short* __restrict__ Kbb,
    unsigned short* __restrict__ Vtb)
{
    __shared__ unsigned short As[128 * 32];
    __shared__ unsigned short Bs[128 * 32];
    const int m0 = blockIdx.x * 128;
    const int panel = blockIdx.y;
    const int which = panel >> 3, h = panel & 7;
    f32x4 acc[4][4] = {};
    mfma_gemm_128(xb + (size_t)m0 * 1024, 1024,
                  Wtb + (size_t)panel * 128 * 1024, 1024, 1024, As, Bs, acc);
    const int tid = threadIdx.x, wave = tid >> 6, lane = tid & 63;
    const int lrow = lane & 15, lquad = lane >> 4;
    const int wm = (wave >> 1) * 64, wn = (wave & 1) * 64;
    #pragma unroll
    for (int i = 0; i < 4; ++i)
        #pragma unroll
        for (int r = 0; r < 4; ++r) {
            int m = m0 + wm + i * 16 + lquad * 4 + r;
            int bb = m >> 12, s = m & 4095;
            int bh = bb * 8 + h;
            size_t rowbase = ((size_t)bh * 4096 + s) * 128;
            #pragma unroll
            for (int j = 0; j < 4; ++j) {
                int col = wn + j * 16 + lrow;
                unsigned short v = f2b(acc[i][j][r]);
                if (which == 0) Kbb[rowbase + col] = v;
                else if (which == 1)
                    Vtb[(((size_t)bh * 8 + (s >> 9)) * 128 + col) * 512 + (s & 511)] = v;
                else Qbb[rowbase + col] = v;
            }
        }
}

// ---------------------------------------------------------------------------
// Output projection: Attb (8192x1024 bf16) @ Woutb (1024x1024 bf16 = Wout^T)
// ---------------------------------------------------------------------------
__global__ __launch_bounds__(256) void gemm_out_mfma(
    const unsigned short* __restrict__ A, const unsigned short* __restrict__ Bt,
    float* __restrict__ C)
{
    __shared__ unsigned short As[128 * 32];
    __shared__ unsigned short Bs[128 * 32];
    const int m0 = blockIdx.x * 128, n0 = blockIdx.y * 128;
    f32x4 acc[4][4] = {};
    mfma_gemm_128(A + (size_t)m0 * 1024, 1024,
                  Bt + (size_t)n0 * 1024, 1024, 1024, As, Bs, acc);
    const int tid = threadIdx.x, wave = tid >> 6, lane = tid & 63;
    const int lrow = lane & 15, lquad = lane >> 4;
    const int wm = (wave >> 1) * 64, wn = (wave & 1) * 64;
    #pragma unroll
    for (int i = 0; i < 4; ++i)
        #pragma unroll
        for (int r = 0; r < 4; ++r) {
            int m = m0 + wm + i * 16 + lquad * 4 + r;
            #pragma unroll
            for (int j = 0; j < 4; ++j)
                C[(size_t)m * 1024 + n0 + wn + j * 16 + lrow] = acc[i][j][r];
        }
}

// ---------------------------------------------------------------------------
// MFMA flash attention over one (bh,seg,qtile of 64 rows). 4 waves x 16 rows.
// Epilogue ADDS (1-gate)*att_dot into Att (scan wrote the mem part already).
// ---------------------------------------------------------------------------
__global__ __launch_bounds__(256) void attn_mfma(
    const unsigned short* __restrict__ Qbb, const unsigned short* __restrict__ Kbb,
    const unsigned short* __restrict__ Vtb, const float* __restrict__ betas,
    float* __restrict__ Att)
{
    __shared__ unsigned short Pl[4][16][72];   // per-wave P tile, padded stride
    const int tid = threadIdx.x, wave = tid >> 6, lane = tid & 63;
    const int n = lane & 15, quad = lane >> 4;
    const int bh = blockIdx.x >> 3, seg = blockIdx.x & 7, qt = blockIdx.y;
    const int b = bh >> 3, h = bh & 7;
    const float scale = 0.08838834764831845f;

    const unsigned short* Qp = Qbb + ((size_t)bh * 4096 + seg * 512 + qt * 64 + wave * 16) * 128;
    const unsigned short* Kp = Kbb + ((size_t)bh * 4096 + seg * 512) * 128;
    const unsigned short* Vp = Vtb + ((size_t)bh * 8 + seg) * 128 * 512;

    bf16x8 aQ[4];
    #pragma unroll
    for (int kc = 0; kc < 4; ++kc)
        aQ[kc] = *(const bf16x8*)(Qp + n * 128 + kc * 32 + quad * 8);

    f32x4 O[8] = {};
    float m_i[4], l_i[4];
    #pragma unroll
    for (int r = 0; r < 4; ++r) { m_i[r] = -1e30f; l_i[r] = 0.f; }

    for (int jt = 0; jt <= qt; ++jt) {
        f32x4 Sf[4] = {};
        #pragma unroll
        for (int kc = 0; kc < 4; ++kc) {
            bf16x8 bK[4];
            #pragma unroll
            for (int ns = 0; ns < 4; ++ns)
                bK[ns] = *(const bf16x8*)(Kp + (size_t)(jt * 64 + ns * 16 + n) * 128 + kc * 32 + quad * 8);
            #pragma unroll
            for (int ns = 0; ns < 4; ++ns)
                Sf[ns] = __builtin_amdgcn_mfma_f32_16x16x32_bf16(aQ[kc], bK[ns], Sf[ns], 0, 0, 0);
        }
        #pragma unroll
        for (int reg = 0; reg < 4; ++reg) {
            int grow = qt * 64 + wave * 16 + quad * 4 + reg;
            float sv[4];
            #pragma unroll
            for (int ns = 0; ns < 4; ++ns) {
                int gcol = jt * 64 + ns * 16 + n;
                sv[ns] = (gcol <= grow) ? Sf[ns][reg] * scale : -1e30f;
            }
            float mx = fmaxf(fmaxf(sv[0], sv[1]), fmaxf(sv[2], sv[3]));
            mx = fmaxf(mx, __shfl_xor(mx, 1));
            mx = fmaxf(mx, __shfl_xor(mx, 2));
            mx = fmaxf(mx, __shfl_xor(mx, 4));
            mx = fmaxf(mx, __shfl_xor(mx, 8));
            float mn = fmaxf(m_i[reg], mx);
            float alpha = __expf(m_i[reg] - mn);
            m_i[reg] = mn;
            float rs = 0.f;
            #pragma unroll
            for (int ns = 0; ns < 4; ++ns) {
                float p = __expf(sv[ns] - mn);
                rs += p;
                Pl[wave][quad * 4 + reg][ns * 16 + n] = f2b(p);
            }
            rs += __shfl_xor(rs, 1);
            rs += __shfl_xor(rs, 2);
            rs += __shfl_xor(rs, 4);
            rs += __shfl_xor(rs, 8);
            l_i[reg] = l_i[reg] * alpha + rs;
            #pragma unroll
            for (int dvs = 0; dvs < 8; ++dvs) O[dvs][reg] *= alpha;
        }
        __syncthreads();
        bf16x8 aP0 = *(const bf16x8*)&Pl[wave][n][quad * 8];
        bf16x8 aP1 = *(const bf16x8*)&Pl[wave][n][32 + quad * 8];
        #pragma unroll
        for (int dvs = 0; dvs < 8; ++dvs) {
            bf16x8 bV0 = *(const bf16x8*)(Vp + (size_t)(dvs * 16 + n) * 512 + jt * 64 + quad * 8);
            bf16x8 bV1 = *(const bf16x8*)(Vp + (size_t)(dvs * 16 + n) * 512 + jt * 64 + 32 + quad * 8);
            O[dvs] = __builtin_amdgcn_mfma_f32_16x16x32_bf16(aP0, bV0, O[dvs], 0, 0, 0);
            O[dvs] = __builtin_amdgcn_mfma_f32_16x16x32_bf16(aP1, bV1, O[dvs], 0, 0, 0);
        }
        __syncthreads();
    }
    float inv[4];
    #pragma unroll
    for (int r = 0; r < 4; ++r) inv[r] = 1.f / l_i[r];
    #pragma unroll
    for (int dvs = 0; dvs < 8; ++dvs) {
        int dv = dvs * 16 + n;
        float g = 1.f - sigmoidf(betas[h * 128 + dv]);
        #pragma unroll
        for (int reg = 0; reg < 4; ++reg) {
            int s = seg * 512 + qt * 64 + wave * 16 + quad * 4 + reg;
            Att[((size_t)b * 4096 + s) * 1024 + h * 128 + dv] += g * O[dvs][reg] * inv[reg];
        }
    }
}

// ---------------------------------------------------------------------------
// MFMA delta-rule scan (runs BEFORE attn_mfma; pure stores into Att).
// wg = (bh, dv-chunk of 32): 64 wgs x 512 thr. memT resident in LDS across
// all segments. Phase 1 software-pipelined: u+1's raw Q/K frags + V values
// prefetched into registers before u's elu/den/MFMA work. Phase 2 A-frags
// (SkT) hoisted above the barrier.
// ---------------------------------------------------------------------------
__global__ __launch_bounds__(512) void scan_mfma(
    const unsigned short* __restrict__ Qbb, const unsigned short* __restrict__ Kbb,
    const unsigned short* __restrict__ Vtb, const unsigned short* __restrict__ SkT,
    const float* __restrict__ betas, float* __restrict__ Att)
{
    __shared__ float memT_f32[32][132];         // [dvloc][dk] master
    __shared__ unsigned short memT_bf[32][136]; // bf16 shadow for b-frags
    __shared__ unsigned short DlT[32][520];     // delta^T [dvloc][s_loc]
    __shared__ float zloc[128];
    const int t = threadIdx.x;
    const int wv = t >> 6, lane = t & 63;
    const int n16 = lane & 15, quad = lane >> 4;
    const int bh = blockIdx.x >> 2, chunk = blockIdx.x & 3;
    const int b = bh >> 3, h = bh & 7;
    const int dv0 = chunk * 32;

    const float g0 = sigmoidf(betas[h * 128 + dv0 + n16]);
    const float g1 = sigmoidf(betas[h * 128 + dv0 + 16 + n16]);

    for (int i = t; i < 32 * 132; i += 512) ((float*)memT_f32)[i] = 0.f;
    if (t < 128) zloc[t] = 1.f / 128.f;
    __syncthreads();

    for (int seg = 0; seg < 8; ++seg) {
        // ---- rebuild bf16 shadow of memT; load z into regs
        {
            int row = t >> 4, col = (t & 15) * 8;
            float4 a = *(float4*)&memT_f32[row][col];
            float4 c = *(float4*)&memT_f32[row][col + 4];
            bf16x8 o;
            o[0] = (short)f2b(a.x); o[1] = (short)f2b(a.y);
            o[2] = (short)f2b(a.z); o[3] = (short)f2b(a.w);
            o[4] = (short)f2b(c.x); o[5] = (short)f2b(c.y);
            o[6] = (short)f2b(c.z); o[7] = (short)f2b(c.w);
            *(bf16x8*)&memT_bf[row][col] = o;
        }
        float zq[32];
        #pragma unroll
        for (int kf = 0; kf < 4; ++kf) {
            float4 z0 = *(float4*)&zloc[kf * 32 + quad * 8];
            float4 z1 = *(float4*)&zloc[kf * 32 + quad * 8 + 4];
            zq[kf * 8 + 0] = z0.x; zq[kf * 8 + 1] = z0.y;
            zq[kf * 8 + 2] = z0.z; zq[kf * 8 + 3] = z0.w;
            zq[kf * 8 + 4] = z1.x; zq[kf * 8 + 5] = z1.y;
            zq[kf * 8 + 6] = z1.z; zq[kf * 8 + 7] = z1.w;
        }
        __syncthreads();

        const size_t segrow = (size_t)bh * 4096 + seg * 512;
        const unsigned short* vbase = Vtb + ((size_t)bh * 8 + seg) * 128 * 512;

        // ---- phase 1 (pipelined): u<4 attmix (Q), u>=4 delta (K)
        bf16x8 cur[4], nxt[4];
        ushort4 vc0 = {}, vc1 = {}, vn0 = {}, vn1 = {};
        {
            const unsigned short* s0 = Qbb + (segrow + (size_t)(wv * 4) * 16 + n16) * 128;
            #pragma unroll
            for (int kf = 0; kf < 4; ++kf)
                cur[kf] = *(const bf16x8*)(s0 + kf * 32 + quad * 8);
        }
        #pragma unroll
        for (int u = 0; u < 8; ++u) {
            const int isq = (u < 4);
            const int mtile = wv * 4 + (u & 3);
            const int sl = mtile * 16 + quad * 4;
            // prefetch u+1
            if (u < 7) {
                const int un = u + 1;
                const int mtn = wv * 4 + (un & 3);
                const unsigned short* sn = ((un < 4) ? Qbb : Kbb)
                    + (segrow + (size_t)mtn * 16 + n16) * 128;
                #pragma unroll
                for (int kf = 0; kf < 4; ++kf)
                    nxt[kf] = *(const bf16x8*)(sn + kf * 32 + quad * 8);
                if (un >= 4) {
                    const int sln = mtn * 16 + quad * 4;
                    vn0 = *(const ushort4*)(vbase + (size_t)(dv0 + n16) * 512 + sln);
                    vn1 = *(const ushort4*)(vbase + (size_t)(dv0 + 16 + n16) * 512 + sln);
                }
            }
            // sigma + denominator
            float den = 0.f;
            bf16x8 afr[4];
            #pragma unroll
            for (int kf = 0; kf < 4; ++kf) {
                bf16x8 a;
                #pragma unroll
                for (int j = 0; j < 8; ++j) {
                    float v = elu1(b2f((unsigned short)cur[kf][j]));
                    den += v * zq[kf * 8 + j];
                    a[j] = (short)f2b(v);
                }
                afr[kf] = a;
            }
            den += __shfl_xor(den, 16);
            den += __shfl_xor(den, 32);
            f32x4 acc0 = {}, acc1 = {};
            #pragma unroll
            for (int kf = 0; kf < 4; ++kf) {
                bf16x8 b0 = *(const bf16x8*)&memT_bf[n16][kf * 32 + quad * 8];
                bf16x8 b1 = *(const bf16x8*)&memT_bf[16 + n16][kf * 32 + quad * 8];
                acc0 = __builtin_amdgcn_mfma_f32_16x16x32_bf16(afr[kf], b0, acc0, 0, 0, 0);
                acc1 = __builtin_amdgcn_mfma_f32_16x16x32_bf16(afr[kf], b1, acc1, 0, 0, 0);
            }
            float ir[4];
            #pragma unroll
            for (int r = 0; r < 4; ++r) ir[r] = 1.f / __shfl(den, quad * 4 + r);
            if (isq) {
                size_t a0 = ((size_t)b * 4096 + seg * 512 + sl) * 1024 + h * 128 + dv0 + n16;
                #pragma unroll
                for (int r = 0; r < 4; ++r) {
                    Att[a0 + (size_t)r * 1024]      = g0 * acc0[r] * ir[r];
                    Att[a0 + (size_t)r * 1024 + 16] = g1 * acc1[r] * ir[r];
                }
            } else {
                const unsigned short* v0p = &vc0.x;
                const unsigned short* v1p = &vc1.x;
                #pragma unroll
                for (int r = 0; r < 4; ++r) {
                    DlT[n16][sl + r]      = f2b(b2f(v0p[r]) - acc0[r] * ir[r]);
                    DlT[16 + n16][sl + r] = f2b(b2f(v1p[r]) - acc1[r] * ir[r]);
                }
            }
            #pragma unroll
            for (int kf = 0; kf < 4; ++kf) cur[kf] = nxt[kf];
            vc0 = vn0; vc1 = vn1;
        }
        // ---- hoist phase-2 A-frag loads (global only) above the barrier
        bf16x8 a2[16];
        {
            const unsigned short* at = SkT
                + ((size_t)bh * 128 + wv * 16 + n16) * 4096 + seg * 512;
            #pragma unroll
            for (int kf = 0; kf < 16; ++kf)
                a2[kf] = *(const bf16x8*)(at + kf * 32 + quad * 8);
        }
        __syncthreads();

        // ---- phase 2: mem += sigma_k^T @ delta (wave wv owns dk tile wv)
        {
            f32x4 u0 = {}, u1 = {}, uz = {};
            bf16x8 onesf;
            #pragma unroll
            for (int j = 0; j < 8; ++j) onesf[j] = (n16 == 0) ? (short)0x3F80 : (short)0;
            #pragma unroll 4
            for (int kf = 0; kf < 16; ++kf) {
                bf16x8 b0 = *(const bf16x8*)&DlT[n16][kf * 32 + quad * 8];
                bf16x8 b1 = *(const bf16x8*)&DlT[16 + n16][kf * 32 + quad * 8];
                u0 = __builtin_amdgcn_mfma_f32_16x16x32_bf16(a2[kf], b0, u0, 0, 0, 0);
                u1 = __builtin_amdgcn_mfma_f32_16x16x32_bf16(a2[kf], b1, u1, 0, 0, 0);
                uz = __builtin_amdgcn_mfma_f32_16x16x32_bf16(a2[kf], onesf, uz, 0, 0, 0);
            }
            float4* p0 = (float4*)&memT_f32[n16][wv * 16 + quad * 4];
            float4* p1 = (float4*)&memT_f32[16 + n16][wv * 16 + quad * 4];
            float4 m0 = *p0, m1 = *p1;
            m0.x += u0[0]; m0.y += u0[1]; m0.z += u0[2]; m0.w += u0[3];
            m1.x += u1[0]; m1.y += u1[1]; m1.z += u1[2]; m1.w += u1[3];
            *p0 = m0; *p1 = m1;
            if (n16 == 0) {
                #pragma unroll
                for (int r = 0; r < 4; ++r) zloc[wv * 16 + quad * 4 + r] += uz[r];
            }
        }
        __syncthreads();
    }
}

extern "C" void kernel_launch(void* const* d_in, const int* in_sizes, int n_in,
                              void* d_out, int out_size, void* d_ws, size_t ws_size,
                              hipStream_t stream) {
    const float* x     = (const float*)d_in[0];
    const float* Wk    = (const float*)d_in[1];
    const float* Wv    = (const float*)d_in[2];
    const float* Wq    = (const float*)d_in[3];
    const float* Wout  = (const float*)d_in[4];
    const float* betas = (const float*)d_in[5];
    float* out = (float*)d_out;
    float* ws = (float*)d_ws;

    // workspace (~101 MB)
    float* Att = ws;                                        // 8388608 f32 (B,S,H*DV)
    unsigned short* Qbb = (unsigned short*)(ws + 8388608);  // 8388608 us (BH,S,128)
    unsigned short* Kbb = Qbb + 8388608;
    unsigned short* Vtb = Kbb + 8388608;                    // (BH,8,128dv,512s)
    unsigned short* SkT = Vtb + 8388608;                    // (BH,128dk,4096s)
    // staging aliases (dead regions at time of use):
    unsigned short* xb    = (unsigned short*)Att;           // consumed before scan writes Att
    unsigned short* Wtb   = xb + 8388608;                   // (3,8,128,1024) W^T bf16
    unsigned short* Attb  = Qbb;                            // Qbb dead after attn
    unsigned short* Woutb = Kbb;                            // Kbb dead after attn

    conv_bf16<<<8192, 256, 0, stream>>>(x, xb);
    transpose_conv<<<dim3(4, 32, 8), 256, 0, stream>>>(Wk, Wtb,               1024, 128);
    transpose_conv<<<dim3(4, 32, 8), 256, 0, stream>>>(Wv, Wtb +  8 * 131072, 1024, 128);
    transpose_conv<<<dim3(4, 32, 8), 256, 0, stream>>>(Wq, Wtb + 16 * 131072, 1024, 128);
    gemm_qkv_mfma<<<dim3(64, 24), 256, 0, stream>>>(xb, Wtb, Qbb, Kbb, Vtb);
    sigma_kT<<<dim3(128, 4, 16), 256, 0, stream>>>(Kbb, SkT);
    scan_mfma<<<64, 512, 0, stream>>>(Qbb, Kbb, Vtb, SkT, betas, Att);
    attn_mfma<<<dim3(128, 8), 256, 0, stream>>>(Qbb, Kbb, Vtb, betas, Att);
    conv_bf16<<<8192, 256, 0, stream>>>(Att, Attb);
    transpose_conv<<<dim3(32, 32, 1), 256, 0, stream>>>(Wout, Woutb, 1024, 1024);
    gemm_out_mfma<<<dim3(64, 8), 256, 0, stream>>>(Attb, Woutb, out);
}

// Round 6
// 409.576 us; speedup vs baseline: 1.2461x; 1.2461x over previous
//
#include <hip/hip_runtime.h>

// Problem constants
#define B_  2
#define S_  4096
#define D_  1024
#define H_  8
#define DK_ 128
#define DV_ 128
#define SEG_ 512
#define NSEG_ 8
#define BH_ 16
#define M_ 8192          // B*S

typedef __attribute__((ext_vector_type(8))) short bf16x8;
typedef __attribute__((ext_vector_type(4))) float f32x4;

__device__ __forceinline__ float elu1(float x) { return x > 0.f ? x + 1.f : __expf(x); }
__device__ __forceinline__ float sigmoidf(float x) { return 1.f / (1.f + __expf(-x)); }

__device__ __forceinline__ unsigned short f2b(float f) {  // RNE fp32->bf16
    union { float f; unsigned int u; } x; x.f = f;
    unsigned int r = x.u + 0x7fffu + ((x.u >> 16) & 1u);
    return (unsigned short)(r >> 16);
}
__device__ __forceinline__ float b2f(unsigned short u) {
    union { unsigned int u; float f; } x; x.u = ((unsigned int)u) << 16; return x.f;
}

__device__ __forceinline__ void gl2lds16(const void* g, void* l) {
    __builtin_amdgcn_global_load_lds(
        (const __attribute__((address_space(1))) void*)g,
        (__attribute__((address_space(3))) void*)l, 16, 0, 0);
}

// ---------------------------------------------------------------------------
// fp32 -> bf16 row-major convert
// ---------------------------------------------------------------------------
__global__ __launch_bounds__(256) void conv_bf16(
    const float* __restrict__ src, unsigned short* __restrict__ dst)
{
    int i = (blockIdx.x * 256 + threadIdx.x) * 4;
    float4 v = *(const float4*)(src + i);
    ushort4 o;
    o.x = f2b(v.x); o.y = f2b(v.y); o.z = f2b(v.z); o.w = f2b(v.w);
    *(ushort4*)(dst + i) = o;
}

// ---------------------------------------------------------------------------
// fp32 (R x C) -> bf16 transposed (C x R). blockIdx.z = matrix index.
// ---------------------------------------------------------------------------
__global__ __launch_bounds__(256) void transpose_conv(
    const float* __restrict__ src, unsigned short* __restrict__ dst, int R, int C)
{
    __shared__ float tile[32][33];
    const size_t moff = (size_t)blockIdx.z * R * C;
    src += moff; dst += moff;
    const int c0 = blockIdx.x * 32, r0 = blockIdx.y * 32;
    const int tx = threadIdx.x & 31, ty = threadIdx.x >> 5;   // 32 x 8
    #pragma unroll
    for (int i = 0; i < 32; i += 8)
        tile[ty + i][tx] = src[(size_t)(r0 + ty + i) * C + c0 + tx];
    __syncthreads();
    #pragma unroll
    for (int i = 0; i < 32; i += 8)
        dst[(size_t)(c0 + ty + i) * R + r0 + tx] = f2b(tile[tx][ty + i]);
}

// ---------------------------------------------------------------------------
// colsum[bh*8+seg][dk] = sum_{s in seg} elu1(K[s][dk])
// ---------------------------------------------------------------------------
__global__ __launch_bounds__(256) void colsum_k(
    const unsigned short* __restrict__ Kbb, float* __restrict__ colsum)
{
    __shared__ float red[32][128];
    const int t = threadIdx.x;
    const int bh = blockIdx.x >> 3, seg = blockIdx.x & 7;
    const unsigned short* Kp = Kbb + ((size_t)bh * 4096 + seg * 512) * 128;
    const int rbase = t >> 3, c0 = (t & 7) * 16;
    float part[16] = {};
    for (int chunk = 0; chunk < 16; ++chunk) {
        const unsigned short* p = Kp + (size_t)(chunk * 32 + rbase) * 128 + c0;
        bf16x8 a = *(const bf16x8*)p;
        bf16x8 b = *(const bf16x8*)(p + 8);
        #pragma unroll
        for (int j = 0; j < 8; ++j) {
            part[j]     += elu1(b2f((unsigned short)a[j]));
            part[j + 8] += elu1(b2f((unsigned short)b[j]));
        }
    }
    #pragma unroll
    for (int j = 0; j < 16; ++j) red[rbase][c0 + j] = part[j];
    __syncthreads();
    if (t < 128) {
        float s = 0.f;
        #pragma unroll
        for (int r = 0; r < 32; ++r) s += red[r][t];
        colsum[(size_t)blockIdx.x * 128 + t] = s;
    }
}

// ---------------------------------------------------------------------------
// zseg[bh*8+seg][dk] = 1/128 + prefix(colsum); den[bh][s] = sigma_k[s].zseg
// ---------------------------------------------------------------------------
__global__ __launch_bounds__(256) void den_z(
    const unsigned short* __restrict__ Kbb, const float* __restrict__ colsum,
    float* __restrict__ den, float* __restrict__ zseg)
{
    __shared__ float zs[128];
    const int t = threadIdx.x;
    const int bh = blockIdx.x >> 3, seg = blockIdx.x & 7;
    if (t < 128) {
        float z = 1.f / 128.f;
        for (int j = 0; j < seg; ++j) z += colsum[(size_t)(bh * 8 + j) * 128 + t];
        zs[t] = z;
        zseg[(size_t)blockIdx.x * 128 + t] = z;
    }
    __syncthreads();
    #pragma unroll
    for (int rr = 0; rr < 2; ++rr) {
        int s = t + rr * 256;
        const unsigned short* kp = Kbb + ((size_t)bh * 4096 + seg * 512 + s) * 128;
        float d = 0.f;
        #pragma unroll 4
        for (int f = 0; f < 16; ++f) {
            bf16x8 a = *(const bf16x8*)(kp + f * 8);
            #pragma unroll
            for (int j = 0; j < 8; ++j)
                d += elu1(b2f((unsigned short)a[j])) * zs[f * 8 + j];
        }
        den[(size_t)bh * 4096 + seg * 512 + s] = d;
    }
}

// ---------------------------------------------------------------------------
// SkT[bh][dk][s] = elu1(K[s][dk]); SkTs = SkT / den[s]
// ---------------------------------------------------------------------------
__global__ __launch_bounds__(256) void sigma_kT2(
    const unsigned short* __restrict__ Kbb, const float* __restrict__ den,
    unsigned short* __restrict__ SkT, unsigned short* __restrict__ SkTs)
{
    __shared__ float tile[32][33];
    __shared__ float rden[32];
    const int bh = blockIdx.z;
    const int s0 = blockIdx.x * 32, dk0 = blockIdx.y * 32;
    const int tx = threadIdx.x & 31, ty = threadIdx.x >> 5;   // 32 x 8
    if (threadIdx.x < 32) rden[threadIdx.x] = 1.f / den[(size_t)bh * 4096 + s0 + threadIdx.x];
    #pragma unroll
    for (int i = 0; i < 32; i += 8)
        tile[ty + i][tx] = elu1(b2f(Kbb[((size_t)bh * 4096 + s0 + ty + i) * 128 + dk0 + tx]));
    __syncthreads();
    #pragma unroll
    for (int i = 0; i < 32; i += 8) {
        float v = tile[tx][ty + i];
        size_t o = ((size_t)bh * 128 + dk0 + ty + i) * 4096 + s0 + tx;
        SkT[o]  = f2b(v);
        SkTs[o] = f2b(v * rden[tx]);
    }
}

// ---------------------------------------------------------------------------
// bf16 MFMA GEMM core: 128x128 tile, BK=32, 16x16x32 MFMA, 4x4 acc per wave.
// ---------------------------------------------------------------------------
__device__ __forceinline__ void mfma_gemm_128(
    const unsigned short* __restrict__ A, int lda,
    const unsigned short* __restrict__ Bt, int ldb, int K,
    unsigned short* As, unsigned short* Bs, f32x4 acc[4][4])
{
    const int tid = threadIdx.x;
    const int wave = tid >> 6, lane = tid & 63;
    const int r4 = lane >> 2, c4 = (lane & 3) * 8;
    const int lrow = lane & 15, lquad = lane >> 4;
    const int wm = (wave >> 1) * 64, wn = (wave & 1) * 64;
    for (int k0 = 0; k0 < K; k0 += 32) {
        #pragma unroll
        for (int i = 0; i < 2; ++i) {
            int ar = wave * 32 + i * 16;
            gl2lds16(A  + (size_t)(ar + r4) * lda + k0 + c4, As + ar * 32);
            gl2lds16(Bt + (size_t)(ar + r4) * ldb + k0 + c4, Bs + ar * 32);
        }
        __syncthreads();
        bf16x8 af[4], bfr[4];
        #pragma unroll
        for (int i = 0; i < 4; ++i)
            af[i] = *(const bf16x8*)(As + (wm + i * 16 + lrow) * 32 + lquad * 8);
        #pragma unroll
        for (int j = 0; j < 4; ++j)
            bfr[j] = *(const bf16x8*)(Bs + (wn + j * 16 + lrow) * 32 + lquad * 8);
        #pragma unroll
        for (int i = 0; i < 4; ++i)
            #pragma unroll
            for (int j = 0; j < 4; ++j)
                acc[i][j] = __builtin_amdgcn_mfma_f32_16x16x32_bf16(af[i], bfr[j], acc[i][j], 0, 0, 0);
        __syncthreads();
    }
}

// ---------------------------------------------------------------------------
// QKV projection: xb (8192x1024 bf16) @ Wtb[panel] (128x1024 bf16 = W^T)
// Outputs: Qbb/Kbb (BH,S,128) row-major; V only as Vtb (BH,8,128dv,512s).
// ---------------------------------------------------------------------------
__global__ __launch_bounds__(256) void gemm_qkv_mfma(
    const unsigned short* __restrict__ xb, const unsigned short* __restrict__ Wtb,
    unsigned short* __restrict__ Qbb, unsigned short* __restrict__ Kbb,
    unsigned short* __restrict__ Vtb)
{
    __shared__ unsigned short As[128 * 32];
    __shared__ unsigned short Bs[128 * 32];
    const int m0 = blockIdx.x * 128;
    const int panel = blockIdx.y;
    const int which = panel >> 3, h = panel & 7;
    f32x4 acc[4][4] = {};
    mfma_gemm_128(xb + (size_t)m0 * 1024, 1024,
                  Wtb + (size_t)panel * 128 * 1024, 1024, 1024, As, Bs, acc);
    const int tid = threadIdx.x, wave = tid >> 6, lane = tid & 63;
    const int lrow = lane & 15, lquad = lane >> 4;
    const int wm = (wave >> 1) * 64, wn = (wave & 1) * 64;
    #pragma unroll
    for (int i = 0; i < 4; ++i)
        #pragma unroll
        for (int r = 0; r < 4; ++r) {
            int m = m0 + wm + i * 16 + lquad * 4 + r;
            int bb = m >> 12, s = m & 4095;
            int bh = bb * 8 + h;
            size_t rowbase = ((size_t)bh * 4096 + s) * 128;
            #pragma unroll
            for (int j = 0; j < 4; ++j) {
                int col = wn + j * 16 + lrow;
                unsigned short v = f2b(acc[i][j][r]);
                if (which == 0) Kbb[rowbase + col] = v;
                else if (which == 1)
                    Vtb[(((size_t)bh * 8 + (s >> 9)) * 128 + col) * 512 + (s & 511)] = v;
                else Qbb[rowbase + col] = v;
            }
        }
}

// ---------------------------------------------------------------------------
// Output projection: Attb (8192x1024 bf16) @ Woutb (1024x1024 bf16 = Wout^T)
// ---------------------------------------------------------------------------
__global__ __launch_bounds__(256) void gemm_out_mfma(
    const unsigned short* __restrict__ A, const unsigned short* __restrict__ Bt,
    float* __restrict__ C)
{
    __shared__ unsigned short As[128 * 32];
    __shared__ unsigned short Bs[128 * 32];
    const int m0 = blockIdx.x * 128, n0 = blockIdx.y * 128;
    f32x4 acc[4][4] = {};
    mfma_gemm_128(A + (size_t)m0 * 1024, 1024,
                  Bt + (size_t)n0 * 1024, 1024, 1024, As, Bs, acc);
    const int tid = threadIdx.x, wave = tid >> 6, lane = tid & 63;
    const int lrow = lane & 15, lquad = lane >> 4;
    const int wm = (wave >> 1) * 64, wn = (wave & 1) * 64;
    #pragma unroll
    for (int i = 0; i < 4; ++i)
        #pragma unroll
        for (int r = 0; r < 4; ++r) {
            int m = m0 + wm + i * 16 + lquad * 4 + r;
            #pragma unroll
            for (int j = 0; j < 4; ++j)
                C[(size_t)m * 1024 + n0 + wn + j * 16 + lrow] = acc[i][j][r];
        }
}

// ---------------------------------------------------------------------------
// Per (bh,seg): E = -(SkT @ SkTs^T-layout) (128x128, bf16)
//               C =  SkT @ Vt              (128x128, fp32)
// K = 512. Shares A staging between both products.
// ---------------------------------------------------------------------------
__global__ __launch_bounds__(256) void ac_gemm(
    const unsigned short* __restrict__ SkT, const unsigned short* __restrict__ SkTs,
    const unsigned short* __restrict__ Vtb,
    unsigned short* __restrict__ Emat, float* __restrict__ Cmat)
{
    __shared__ unsigned short As[128 * 32];
    __shared__ unsigned short Bs1[128 * 32];
    __shared__ unsigned short Bs2[128 * 32];
    const int bh = blockIdx.x >> 3, seg = blockIdx.x & 7;
    const unsigned short* Ap  = SkT  + (size_t)bh * 128 * 4096 + seg * 512;
    const unsigned short* B1p = SkTs + (size_t)bh * 128 * 4096 + seg * 512;
    const unsigned short* B2p = Vtb  + (size_t)blockIdx.x * 128 * 512;
    const int tid = threadIdx.x;
    const int wave = tid >> 6, lane = tid & 63;
    const int r4 = lane >> 2, c4 = (lane & 3) * 8;
    const int lrow = lane & 15, lquad = lane >> 4;
    const int wm = (wave >> 1) * 64, wn = (wave & 1) * 64;
    f32x4 e[4][4] = {}, c[4][4] = {};
    for (int k0 = 0; k0 < 512; k0 += 32) {
        #pragma unroll
        for (int i = 0; i < 2; ++i) {
            int ar = wave * 32 + i * 16;
            gl2lds16(Ap  + (size_t)(ar + r4) * 4096 + k0 + c4, As  + ar * 32);
            gl2lds16(B1p + (size_t)(ar + r4) * 4096 + k0 + c4, Bs1 + ar * 32);
            gl2lds16(B2p + (size_t)(ar + r4) * 512  + k0 + c4, Bs2 + ar * 32);
        }
        __syncthreads();
        bf16x8 af[4], b1[4], b2[4];
        #pragma unroll
        for (int i = 0; i < 4; ++i)
            af[i] = *(const bf16x8*)(As + (wm + i * 16 + lrow) * 32 + lquad * 8);
        #pragma unroll
        for (int j = 0; j < 4; ++j) {
            b1[j] = *(const bf16x8*)(Bs1 + (wn + j * 16 + lrow) * 32 + lquad * 8);
            b2[j] = *(const bf16x8*)(Bs2 + (wn + j * 16 + lrow) * 32 + lquad * 8);
        }
        #pragma unroll
        for (int i = 0; i < 4; ++i)
            #pragma unroll
            for (int j = 0; j < 4; ++j) {
                e[i][j] = __builtin_amdgcn_mfma_f32_16x16x32_bf16(af[i], b1[j], e[i][j], 0, 0, 0);
                c[i][j] = __builtin_amdgcn_mfma_f32_16x16x32_bf16(af[i], b2[j], c[i][j], 0, 0, 0);
            }
        __syncthreads();
    }
    #pragma unroll
    for (int i = 0; i < 4; ++i)
        #pragma unroll
        for (int r = 0; r < 4; ++r) {
            int m = wm + i * 16 + lquad * 4 + r;
            #pragma unroll
            for (int j = 0; j < 4; ++j) {
                int nn = wn + j * 16 + lrow;
                size_t o = (size_t)blockIdx.x * 16384 + (size_t)m * 128 + nn;
                Emat[o] = f2b(-e[i][j][r]);
                Cmat[o] = c[i][j][r];
            }
        }
}

// ---------------------------------------------------------------------------
// Sequential scan: per bh, mem (128x128) lives in registers across 8 steps.
// mem_{i+1} = mem_i + E_i@mem_i + C_i. Snapshots Memb[bh][i] (bf16, [dv][dk]).
// 16 wgs x 512 thr; only 8 serial 128^3 matmuls of real latency.
// ---------------------------------------------------------------------------
__global__ __launch_bounds__(512) void scan_step(
    const unsigned short* __restrict__ Emat, const float* __restrict__ Cmat,
    unsigned short* __restrict__ Memb)
{
    __shared__ unsigned short msh[128][136];   // memT shadow [v][k], padded
    const int t = threadIdx.x;
    const int wv = t >> 6, lane = t & 63;
    const int n16 = lane & 15, quad = lane >> 4;
    const int bh = blockIdx.x;
    f32x4 macc[8] = {};    // mem[k' = wv*16+quad*4+r][v = vt*16+n16]
    for (int seg = 0; seg < 8; ++seg) {
        unsigned short* gm = Memb + ((size_t)(bh * 8 + seg)) * 16384;
        #pragma unroll
        for (int vt = 0; vt < 8; ++vt) {
            ushort4 o;
            o.x = f2b(macc[vt][0]); o.y = f2b(macc[vt][1]);
            o.z = f2b(macc[vt][2]); o.w = f2b(macc[vt][3]);
            *(ushort4*)&msh[vt * 16 + n16][wv * 16 + quad * 4] = o;
            *(ushort4*)(gm + (size_t)(vt * 16 + n16) * 128 + wv * 16 + quad * 4) = o;
        }
        if (seg == 7) break;
        __syncthreads();
        const unsigned short* Ep = Emat + ((size_t)(bh * 8 + seg)) * 16384
                                 + (size_t)(wv * 16 + n16) * 128;
        bf16x8 ea[4];
        #pragma unroll
        for (int kf = 0; kf < 4; ++kf)
            ea[kf] = *(const bf16x8*)(Ep + kf * 32 + quad * 8);
        const float* Cp = Cmat + ((size_t)(bh * 8 + seg)) * 16384
                        + (size_t)(wv * 16 + quad * 4) * 128;
        #pragma unroll
        for (int vt = 0; vt < 8; ++vt)
            #pragma unroll
            for (int r = 0; r < 4; ++r)
                macc[vt][r] += Cp[(size_t)r * 128 + vt * 16 + n16];
        #pragma unroll
        for (int vt = 0; vt < 8; ++vt)
            #pragma unroll
            for (int kf = 0; kf < 4; ++kf) {
                bf16x8 bfr = *(const bf16x8*)&msh[vt * 16 + n16][kf * 32 + quad * 8];
                macc[vt] = __builtin_amdgcn_mfma_f32_16x16x32_bf16(ea[kf], bfr, macc[vt], 0, 0, 0);
            }
        __syncthreads();
    }
}

// ---------------------------------------------------------------------------
// Flash attention + memory-attention apply, writes final bf16 Attb.
// out = gate*(sigma_q@mem_seg)/(sigma_q.z_seg) + (1-gate)*softmax(QK^T)V
// ---------------------------------------------------------------------------
__global__ __launch_bounds__(256) void attn_out(
    const unsigned short* __restrict__ Qbb, const unsigned short* __restrict__ Kbb,
    const unsigned short* __restrict__ Vtb, const unsigned short* __restrict__ Memb,
    const float* __restrict__ zseg, const float* __restrict__ betas,
    unsigned short* __restrict__ Attb)
{
    __shared__ unsigned short Pl[4][16][72];   // per-wave P tile, padded stride
    const int tid = threadIdx.x, wave = tid >> 6, lane = tid & 63;
    const int n = lane & 15, quad = lane >> 4;
    const int bh = blockIdx.x >> 3, seg = blockIdx.x & 7, qt = blockIdx.y;
    const int b = bh >> 3, h = bh & 7;
    const float scale = 0.08838834764831845f;

    const unsigned short* Qp = Qbb + ((size_t)bh * 4096 + seg * 512 + qt * 64 + wave * 16) * 128;
    const unsigned short* Kp = Kbb + ((size_t)bh * 4096 + seg * 512) * 128;
    const unsigned short* Vp = Vtb + ((size_t)bh * 8 + seg) * 128 * 512;

    bf16x8 aQ[4];
    #pragma unroll
    for (int kc = 0; kc < 4; ++kc)
        aQ[kc] = *(const bf16x8*)(Qp + n * 128 + kc * 32 + quad * 8);

    f32x4 O[8] = {};
    float m_i[4], l_i[4];
    #pragma unroll
    for (int r = 0; r < 4; ++r) { m_i[r] = -1e30f; l_i[r] = 0.f; }

    for (int jt = 0; jt <= qt; ++jt) {
        f32x4 Sf[4] = {};
        #pragma unroll
        for (int kc = 0; kc < 4; ++kc) {
            bf16x8 bK[4];
            #pragma unroll
            for (int ns = 0; ns < 4; ++ns)
                bK[ns] = *(const bf16x8*)(Kp + (size_t)(jt * 64 + ns * 16 + n) * 128 + kc * 32 + quad * 8);
            #pragma unroll
            for (int ns = 0; ns < 4; ++ns)
                Sf[ns] = __builtin_amdgcn_mfma_f32_16x16x32_bf16(aQ[kc], bK[ns], Sf[ns], 0, 0, 0);
        }
        #pragma unroll
        for (int reg = 0; reg < 4; ++reg) {
            int grow = qt * 64 + wave * 16 + quad * 4 + reg;
            float sv[4];
            #pragma unroll
            for (int ns = 0; ns < 4; ++ns) {
                int gcol = jt * 64 + ns * 16 + n;
                sv[ns] = (gcol <= grow) ? Sf[ns][reg] * scale : -1e30f;
            }
            float mx = fmaxf(fmaxf(sv[0], sv[1]), fmaxf(sv[2], sv[3]));
            mx = fmaxf(mx, __shfl_xor(mx, 1));
            mx = fmaxf(mx, __shfl_xor(mx, 2));
            mx = fmaxf(mx, __shfl_xor(mx, 4));
            mx = fmaxf(mx, __shfl_xor(mx, 8));
            float mn = fmaxf(m_i[reg], mx);
            float alpha = __expf(m_i[reg] - mn);
            m_i[reg] = mn;
            float rs = 0.f;
            #pragma unroll
            for (int ns = 0; ns < 4; ++ns) {
                float p = __expf(sv[ns] - mn);
                rs += p;
                Pl[wave][quad * 4 + reg][ns * 16 + n] = f2b(p);
            }
            rs += __shfl_xor(rs, 1);
            rs += __shfl_xor(rs, 2);
            rs += __shfl_xor(rs, 4);
            rs += __shfl_xor(rs, 8);
            l_i[reg] = l_i[reg] * alpha + rs;
            #pragma unroll
            for (int dvs = 0; dvs < 8; ++dvs) O[dvs][reg] *= alpha;
        }
        __syncthreads();
        bf16x8 aP0 = *(const bf16x8*)&Pl[wave][n][quad * 8];
        bf16x8 aP1 = *(const bf16x8*)&Pl[wave][n][32 + quad * 8];
        #pragma unroll
        for (int dvs = 0; dvs < 8; ++dvs) {
            bf16x8 bV0 = *(const bf16x8*)(Vp + (size_t)(dvs * 16 + n) * 512 + jt * 64 + quad * 8);
            bf16x8 bV1 = *(const bf16x8*)(Vp + (size_t)(dvs * 16 + n) * 512 + jt * 64 + 32 + quad * 8);
            O[dvs] = __builtin_amdgcn_mfma_f32_16x16x32_bf16(aP0, bV0, O[dvs], 0, 0, 0);
            O[dvs] = __builtin_amdgcn_mfma_f32_16x16x32_bf16(aP1, bV1, O[dvs], 0, 0, 0);
        }
        __syncthreads();
    }
    // ---- apply: sigma_q @ mem_seg / (sigma_q . z_seg)
    const float* zp = zseg + (size_t)(bh * 8 + seg) * 128;
    float den = 0.f;
    bf16x8 aS[4];
    #pragma unroll
    for (int kc = 0; kc < 4; ++kc) {
        float4 z0 = *(const float4*)(zp + kc * 32 + quad * 8);
        float4 z1 = *(const float4*)(zp + kc * 32 + quad * 8 + 4);
        float zv[8] = {z0.x, z0.y, z0.z, z0.w, z1.x, z1.y, z1.z, z1.w};
        bf16x8 a;
        #pragma unroll
        for (int j = 0; j < 8; ++j) {
            float s = elu1(b2f((unsigned short)aQ[kc][j]));
            den += s * zv[j];
            a[j] = (short)f2b(s);
        }
        aS[kc] = a;
    }
    den += __shfl_xor(den, 16);
    den += __shfl_xor(den, 32);
    const unsigned short* Mp = Memb + (size_t)(bh * 8 + seg) * 16384;
    f32x4 Om[8] = {};
    #pragma unroll
    for (int dvs = 0; dvs < 8; ++dvs)
        #pragma unroll
        for (int kc = 0; kc < 4; ++kc) {
            bf16x8 bm = *(const bf16x8*)(Mp + (size_t)(dvs * 16 + n) * 128 + kc * 32 + quad * 8);
            Om[dvs] = __builtin_amdgcn_mfma_f32_16x16x32_bf16(aS[kc], bm, Om[dvs], 0, 0, 0);
        }
    float irm[4], inv[4];
    #pragma unroll
    for (int r = 0; r < 4; ++r) {
        irm[r] = 1.f / __shfl(den, quad * 4 + r);
        inv[r] = 1.f / l_i[r];
    }
    #pragma unroll
    for (int dvs = 0; dvs < 8; ++dvs) {
        int dv = dvs * 16 + n;
        float g = sigmoidf(betas[h * 128 + dv]);
        #pragma unroll
        for (int r = 0; r < 4; ++r) {
            int s = seg * 512 + qt * 64 + wave * 16 + quad * 4 + r;
            float val = g * Om[dvs][r] * irm[r] + (1.f - g) * O[dvs][r] * inv[r];
            Attb[((size_t)b * 4096 + s) * 1024 + h * 128 + dv] = f2b(val);
        }
    }
}

extern "C" void kernel_launch(void* const* d_in, const int* in_sizes, int n_in,
                              void* d_out, int out_size, void* d_ws, size_t ws_size,
                              hipStream_t stream) {
    const float* x     = (const float*)d_in[0];
    const float* Wk    = (const float*)d_in[1];
    const float* Wv    = (const float*)d_in[2];
    const float* Wq    = (const float*)d_in[3];
    const float* Wout  = (const float*)d_in[4];
    const float* betas = (const float*)d_in[5];
    float* out = (float*)d_out;

    // workspace (~97 MB)
    unsigned short* Qbb  = (unsigned short*)d_ws;           // 16MB (BH,S,128)
    unsigned short* Kbb  = Qbb + 8388608;                   // 16MB
    unsigned short* Vtb  = Kbb + 8388608;                   // 16MB (BH,8,128dv,512s)
    unsigned short* SkT  = Vtb + 8388608;                   // 16MB (BH,128dk,4096s)
    unsigned short* SkTs = SkT + 8388608;                   // 16MB
    unsigned short* Emat = SkTs + 8388608;                  // 4MB  (BH*8,128,128)
    unsigned short* Memb = Emat + 2097152;                  // 4MB  (BH*8,128dv,128dk)
    float* Cmat   = (float*)(Memb + 2097152);               // 8MB  (BH*8,128,128)
    float* colsum = Cmat + 2097152;                         // 64KB (BH*8,128)
    float* zseg   = colsum + 16384;                         // 64KB
    float* den    = zseg + 16384;                           // 256KB (BH,4096)
    // aliases into dead regions:
    unsigned short* xb    = SkT;      // consumed by gemm_qkv before sigma_kT2 writes SkT
    unsigned short* Wtb   = SkTs;     // consumed by gemm_qkv
    unsigned short* Attb  = SkT;      // SkT dead after ac_gemm
    unsigned short* Woutb = SkTs;     // SkTs dead after ac_gemm

    conv_bf16<<<8192, 256, 0, stream>>>(x, xb);
    transpose_conv<<<dim3(4, 32, 8), 256, 0, stream>>>(Wk, Wtb,               1024, 128);
    transpose_conv<<<dim3(4, 32, 8), 256, 0, stream>>>(Wv, Wtb +  8 * 131072, 1024, 128);
    transpose_conv<<<dim3(4, 32, 8), 256, 0, stream>>>(Wq, Wtb + 16 * 131072, 1024, 128);
    gemm_qkv_mfma<<<dim3(64, 24), 256, 0, stream>>>(xb, Wtb, Qbb, Kbb, Vtb);
    colsum_k<<<128, 256, 0, stream>>>(Kbb, colsum);
    den_z<<<128, 256, 0, stream>>>(Kbb, colsum, den, zseg);
    sigma_kT2<<<dim3(128, 4, 16), 256, 0, stream>>>(Kbb, den, SkT, SkTs);
    ac_gemm<<<128, 256, 0, stream>>>(SkT, SkTs, Vtb, Emat, Cmat);
    scan_step<<<16, 512, 0, stream>>>(Emat, Cmat, Memb);
    attn_out<<<dim3(128, 8), 256, 0, stream>>>(Qbb, Kbb, Vtb, Memb, zseg, betas, Attb);
    transpose_conv<<<dim3(32, 32, 1), 256, 0, stream>>>(Wout, Woutb, 1024, 1024);
    gemm_out_mfma<<<dim3(64, 8), 256, 0, stream>>>(Attb, Woutb, out);
}